// Round 1
// baseline (47.498 us; speedup 1.0000x reference)
//
#include <hip/hip_runtime.h>
#include <hip/hip_bf16.h>

// LightweightConv1d: depthwise conv1d, K=7, PAD=3, per-head softmax weights.
// x: (B=8, C=1024, T=4096) fp32; weight: (H=16, 1, K=7) fp32; bias: (C,) fp32.
// out[b,c,t] = sum_k softmax(w[c%H])[k] * x[b,c,t+k-3] + bias[c]

constexpr int Bsz = 8;
constexpr int Csz = 1024;
constexpr int Tsz = 4096;
constexpr int Hsz = 16;
constexpr int Ksz = 7;
constexpr int PADsz = 3;

constexpr int TILE = 1024;          // elements of T per block
constexpr int THREADS = 256;        // 4 outputs per thread (float4)
constexpr int TILES_PER_ROW = Tsz / TILE;  // 4

__global__ __launch_bounds__(THREADS)
void lconv1d_kernel(const float* __restrict__ x,
                    const float* __restrict__ weight,
                    const float* __restrict__ bias,
                    float* __restrict__ out) {
    // LDS layout: lds[i] = x[row, t0 - 4 + i]  (left pad of 4 keeps float4
    // stores/loads 16B-aligned; only indices 1..1030 are actually consumed)
    __shared__ __align__(16) float lds[4 + TILE + 4];

    const int bid  = blockIdx.x;
    const int tile = bid % TILES_PER_ROW;
    const int row  = bid / TILES_PER_ROW;     // row = b*C + c, 0..B*C-1
    const int c    = row % Csz;
    const int h    = c % Hsz;
    const int t0   = tile * TILE;
    const int tid  = threadIdx.x;

    const float* __restrict__ xrow = x + (size_t)row * Tsz;

    // ---- main tile load: aligned float4 global -> aligned float4 LDS ----
    {
        const float4 v = *reinterpret_cast<const float4*>(xrow + t0 + tid * 4);
        *reinterpret_cast<float4*>(&lds[4 + tid * 4]) = v;
    }
    // ---- halos (3 each side, zero at row boundaries) ----
    if (tid < PADsz) {
        // left halo: lds[1+tid] = x[t0-3+tid]
        const int g = t0 - PADsz + tid;
        lds[1 + tid] = (g >= 0) ? xrow[g] : 0.0f;
    } else if (tid < 2 * PADsz) {
        // right halo: lds[4+TILE + (tid-3)] = x[t0+TILE + (tid-3)]
        const int j = tid - PADsz;
        const int g = t0 + TILE + j;
        lds[4 + TILE + j] = (g < Tsz) ? xrow[g] : 0.0f;
    }

    // ---- per-head softmax over the 7 taps (uniform per block, cheap) ----
    float w[Ksz];
    {
        const float* wh = weight + h * Ksz;
        float m = wh[0];
        #pragma unroll
        for (int k = 1; k < Ksz; ++k) m = fmaxf(m, wh[k]);
        float s = 0.0f;
        #pragma unroll
        for (int k = 0; k < Ksz; ++k) { w[k] = __expf(wh[k] - m); s += w[k]; }
        const float inv = 1.0f / s;
        #pragma unroll
        for (int k = 0; k < Ksz; ++k) w[k] *= inv;
    }
    const float bc = bias[c];

    __syncthreads();

    // ---- compute: 12 staged floats -> 4 outputs ----
    const float4 a0 = *reinterpret_cast<const float4*>(&lds[tid * 4 + 0]);
    const float4 a1 = *reinterpret_cast<const float4*>(&lds[tid * 4 + 4]);
    const float4 a2 = *reinterpret_cast<const float4*>(&lds[tid * 4 + 8]);
    float r[12] = {a0.x, a0.y, a0.z, a0.w,
                   a1.x, a1.y, a1.z, a1.w,
                   a2.x, a2.y, a2.z, a2.w};
    // output t = t0 + tid*4 + j needs x[t-3..t+3] = lds[tid*4 + j + 1 .. +7]
    float4 o;
    float* op = &o.x;
    #pragma unroll
    for (int j = 0; j < 4; ++j) {
        float acc = bc;
        #pragma unroll
        for (int k = 0; k < Ksz; ++k) acc = fmaf(w[k], r[j + 1 + k], acc);
        op[j] = acc;
    }
    *reinterpret_cast<float4*>(out + (size_t)row * Tsz + t0 + tid * 4) = o;
}

extern "C" void kernel_launch(void* const* d_in, const int* in_sizes, int n_in,
                              void* d_out, int out_size, void* d_ws, size_t ws_size,
                              hipStream_t stream) {
    const float* x      = (const float*)d_in[0];
    const float* weight = (const float*)d_in[1];
    const float* bias   = (const float*)d_in[2];
    float* out          = (float*)d_out;

    const int nblocks = Bsz * Csz * TILES_PER_ROW;  // 32768
    lconv1d_kernel<<<nblocks, THREADS, 0, stream>>>(x, weight, bias, out);
}

// Round 2
// 44.448 us; speedup vs baseline: 1.0686x; 1.0686x over previous
//
#include <hip/hip_runtime.h>
#include <hip/hip_bf16.h>

// LightweightConv1d: depthwise conv1d, K=7, PAD=3, per-head softmax weights.
// x: (B=8, C=1024, T=4096) fp32; weight: (H=16, 1, 7) fp32; bias: (C,) fp32.
// out[b,c,t] = sum_k softmax(w[c%16])[k] * x[b,c,t+k-3] + bias[c]
//
// R2: no LDS, no barrier. Each thread produces 8 outputs as two float4
// chunks 1024 apart; inputs come from 3 aligned overlapping float4 global
// loads per chunk (offsets -16B/0/+16B). Overlap bytes are L1/L2 hits, so
// HBM traffic stays at the 1x ideal (134 MB read + 134 MB write).

constexpr int Bsz = 8;
constexpr int Csz = 1024;
constexpr int Tsz = 4096;
constexpr int Hsz = 16;
constexpr int Ksz = 7;

constexpr int THREADS = 256;
constexpr int TILE = 2048;               // T-span per block
constexpr int CHUNK = 1024;              // distance between a thread's 2 chunks
constexpr int TILES_PER_ROW = Tsz / TILE;  // 2

__global__ __launch_bounds__(THREADS)
void lconv1d_kernel(const float* __restrict__ x,
                    const float* __restrict__ weight,
                    const float* __restrict__ bias,
                    float* __restrict__ out) {
    const int bid  = blockIdx.x;
    const int tile = bid % TILES_PER_ROW;
    const int row  = bid / TILES_PER_ROW;     // b*C + c
    const int c    = row % Csz;
    const int h    = c % Hsz;
    const int t0   = tile * TILE;
    const int tid  = threadIdx.x;

    const float* __restrict__ xrow = x + (size_t)row * Tsz;
    float* __restrict__ orow       = out + (size_t)row * Tsz;

    const int p0 = t0 + tid * 4;       // chunk A: outputs p0..p0+3
    const int p1 = p0 + CHUNK;         // chunk B: outputs p1..p1+3

    // Geometry facts (TILE=2048, CHUNK=1024, t0 in {0,2048}):
    //   chunk A left edge  (p0==0)        : only tile 0, tid 0
    //   chunk A right edge                : impossible (p0+7 <= 3075)
    //   chunk B left edge                 : impossible (p1 >= 1024)
    //   chunk B right edge (p1+4 >= Tsz)  : only last tile, tid 255
    const bool lA = (p0 == 0);
    const bool rB = (p1 + 4 >= Tsz);

    // ---- issue all 6 loads up front (independent chains, aligned 16B) ----
    const float4 a0 = *reinterpret_cast<const float4*>(xrow + (lA ? p0 : p0 - 4));
    const float4 a1 = *reinterpret_cast<const float4*>(xrow + p0);
    const float4 a2 = *reinterpret_cast<const float4*>(xrow + p0 + 4);
    const float4 b0 = *reinterpret_cast<const float4*>(xrow + p1 - 4);
    const float4 b1 = *reinterpret_cast<const float4*>(xrow + p1);
    const float4 b2 = *reinterpret_cast<const float4*>(xrow + (rB ? p1 : p1 + 4));

    // ---- per-head softmax over the 7 taps (block-uniform, scalar regs) ----
    float w[Ksz];
    {
        const float* wh = weight + h * Ksz;
        float m = wh[0];
        #pragma unroll
        for (int k = 1; k < Ksz; ++k) m = fmaxf(m, wh[k]);
        float s = 0.0f;
        #pragma unroll
        for (int k = 0; k < Ksz; ++k) { w[k] = __expf(wh[k] - m); s += w[k]; }
        const float inv = 1.0f / s;
        #pragma unroll
        for (int k = 0; k < Ksz; ++k) w[k] *= inv;
    }
    const float bc = bias[c];

    // ---- materialize windows with branch-free edge zeroing ----
    // ra[i] = x[p0-4+i] (zero-padded), rb[i] = x[p1-4+i]
    const float zA = lA ? 0.0f : 1.0f;   // multiply-select avoids branches
    float ra[12] = {a0.x * zA, a0.y * zA, a0.z * zA, a0.w * zA,
                    a1.x, a1.y, a1.z, a1.w,
                    a2.x, a2.y, a2.z, a2.w};
    const float zB = rB ? 0.0f : 1.0f;
    float rb[12] = {b0.x, b0.y, b0.z, b0.w,
                    b1.x, b1.y, b1.z, b1.w,
                    b2.x * zB, b2.y * zB, b2.z * zB, b2.w * zB};

    // ---- compute: output p+j needs r[j+1 .. j+7] ----
    float4 oA, oB;
    float* oap = &oA.x;
    float* obp = &oB.x;
    #pragma unroll
    for (int j = 0; j < 4; ++j) {
        float accA = bc, accB = bc;
        #pragma unroll
        for (int k = 0; k < Ksz; ++k) {
            accA = fmaf(w[k], ra[j + 1 + k], accA);
            accB = fmaf(w[k], rb[j + 1 + k], accB);
        }
        oap[j] = accA;
        obp[j] = accB;
    }

    *reinterpret_cast<float4*>(orow + p0) = oA;
    *reinterpret_cast<float4*>(orow + p1) = oB;
}

extern "C" void kernel_launch(void* const* d_in, const int* in_sizes, int n_in,
                              void* d_out, int out_size, void* d_ws, size_t ws_size,
                              hipStream_t stream) {
    const float* x      = (const float*)d_in[0];
    const float* weight = (const float*)d_in[1];
    const float* bias   = (const float*)d_in[2];
    float* out          = (float*)d_out;

    const int nblocks = Bsz * Csz * TILES_PER_ROW;  // 16384
    lconv1d_kernel<<<nblocks, THREADS, 0, stream>>>(x, weight, bias, out);
}

// Round 4
// 43.242 us; speedup vs baseline: 1.0984x; 1.0279x over previous
//
#include <hip/hip_runtime.h>
#include <hip/hip_bf16.h>

// LightweightConv1d: depthwise conv1d, K=7, PAD=3, per-head softmax weights.
// x: (B=8, C=1024, T=4096) fp32; weight: (H=16, 1, 7) fp32; bias: (C,) fp32.
// out[b,c,t] = sum_k softmax(w[c%16])[k] * x[b,c,t+k-3] + bias[c]
//
// R3b: one block per (b,c) row; each thread produces 16 outputs as four
// float4 chunks 1024 apart. 12 independent aligned float4 loads up front
// (max MLP); overlap bytes are L1 hits so HBM stays at the 1x ideal.
// Non-temporal stores (via native ext_vector f32x4 — HIP_vector_type is
// rejected by the builtin) keep the 134 MB write stream out of L3.

constexpr int Bsz = 8;
constexpr int Csz = 1024;
constexpr int Tsz = 4096;
constexpr int Hsz = 16;
constexpr int Ksz = 7;

constexpr int THREADS = 256;
constexpr int NCH = 4;                 // chunks per thread, 1024 apart

typedef float f32x4 __attribute__((ext_vector_type(4)));

__global__ __launch_bounds__(THREADS)
void lconv1d_kernel(const float* __restrict__ x,
                    const float* __restrict__ weight,
                    const float* __restrict__ bias,
                    float* __restrict__ out) {
    const int row = blockIdx.x;            // b*C + c
    const int c   = row % Csz;
    const int h   = c % Hsz;
    const int tid = threadIdx.x;

    const float* __restrict__ xrow = x + (size_t)row * Tsz;
    float* __restrict__ orow       = out + (size_t)row * Tsz;

    // ---- issue all 12 loads up front (independent, aligned 16B) ----
    // chunk ch covers outputs p..p+3, p = tid*4 + ch*1024.
    // Edges: only (ch==0, tid==0) touches t<0; only (ch==3, tid==255) t>=Tsz.
    f32x4 A[NCH][3];
    #pragma unroll
    for (int ch = 0; ch < NCH; ++ch) {
        const int p = tid * 4 + ch * 1024;
        const bool lE = (p == 0);
        const bool rE = (p + 4 >= Tsz);
        A[ch][0] = *reinterpret_cast<const f32x4*>(xrow + (lE ? p : p - 4));
        A[ch][1] = *reinterpret_cast<const f32x4*>(xrow + p);
        A[ch][2] = *reinterpret_cast<const f32x4*>(xrow + (rE ? p : p + 4));
    }

    // ---- per-head softmax over the 7 taps (block-uniform) ----
    float w[Ksz];
    {
        const float* wh = weight + h * Ksz;
        float m = wh[0];
        #pragma unroll
        for (int k = 1; k < Ksz; ++k) m = fmaxf(m, wh[k]);
        float s = 0.0f;
        #pragma unroll
        for (int k = 0; k < Ksz; ++k) { w[k] = __expf(wh[k] - m); s += w[k]; }
        const float inv = 1.0f / s;
        #pragma unroll
        for (int k = 0; k < Ksz; ++k) w[k] *= inv;
    }
    const float bc = bias[c];

    // ---- compute + store per chunk ----
    #pragma unroll
    for (int ch = 0; ch < NCH; ++ch) {
        const int p = tid * 4 + ch * 1024;
        const bool lE = (p == 0);
        const bool rE = (p + 4 >= Tsz);
        const float zL = lE ? 0.0f : 1.0f;   // branch-free edge zeroing
        const float zR = rE ? 0.0f : 1.0f;
        const f32x4 a0 = A[ch][0];
        const f32x4 a1 = A[ch][1];
        const f32x4 a2 = A[ch][2];
        // r[i] = x[p-4+i], zero-padded at row ends
        const float r[12] = {a0.x * zL, a0.y * zL, a0.z * zL, a0.w * zL,
                             a1.x, a1.y, a1.z, a1.w,
                             a2.x * zR, a2.y * zR, a2.z * zR, a2.w * zR};
        f32x4 o;
        #pragma unroll
        for (int j = 0; j < 4; ++j) {
            float acc = bc;
            #pragma unroll
            for (int k = 0; k < Ksz; ++k) acc = fmaf(w[k], r[j + 1 + k], acc);
            o[j] = acc;
        }
        __builtin_nontemporal_store(o, reinterpret_cast<f32x4*>(orow + p));
    }
}

extern "C" void kernel_launch(void* const* d_in, const int* in_sizes, int n_in,
                              void* d_out, int out_size, void* d_ws, size_t ws_size,
                              hipStream_t stream) {
    const float* x      = (const float*)d_in[0];
    const float* weight = (const float*)d_in[1];
    const float* bias   = (const float*)d_in[2];
    float* out          = (float*)d_out;

    const int nblocks = Bsz * Csz;  // 8192, one per (b,c) row
    lconv1d_kernel<<<nblocks, THREADS, 0, stream>>>(x, weight, bias, out);
}